// Round 19
// baseline (183.584 us; speedup 1.0000x reference)
//
#include <hip/hip_runtime.h>
#include <hip/hip_fp16.h>

#define LQ 384
#define DF 64
#define NWIN 16
#define PERW 15      // NG + NF
#define STEPW 16     // 1 + NG + NF
#define NPAIR 240    // NWIN * PERW
#define NWAVE 6      // row-slabs (producer waves and consumer waves each)
#define PW 64        // panel width (cols per round) -- optimal for step count
#define NPANEL 6     // 384 / PW
#define NROUND2 12   // NPANEL + NWAVE - 1 + 1 (producer lead)
#define DRS 70       // fp16 D-tile ROW stride (halfs); 140 B -> coprime bank walk
#define C2  0.28853900817779268f   // 1/(5*ln2)  (pre-scale: R' = R*C2)
#define L2C 3.4657359027997265f    // 5*ln2      (unscale at extraction)
#define BIGS (1e9f * C2)           // BIG in scaled domain

typedef _Float16 h16x8 __attribute__((ext_vector_type(8)));
typedef float    f32x16 __attribute__((ext_vector_type(16)));

__device__ __forceinline__ float fexp2(float x) { return __builtin_amdgcn_exp2f(x); }
__device__ __forceinline__ float flog2(float x) { return __builtin_amdgcn_logf(x); }

// wave_shr:1 -- lane l gets lane l-1's value (VALU pipe). lane0 keeps own (fixed up).
__device__ __forceinline__ float wshr1f(float x) {
  int xi = __float_as_int(x);
  return __int_as_float(__builtin_amdgcn_update_dpp(xi, xi, 0x138, 0xF, 0xF, false));
}
__device__ __forceinline__ float rdlane(float v, int l) {
  return __int_as_float(__builtin_amdgcn_readlane(__float_as_int(v), l));
}

// ---------------------------------------------------------------------------
// Producer-consumer soft-DTW, PW=64, MFMA producer (r18-validated layouts).
// Producers: per round, 2x2 tiles of v_mfma_f32_32x32x16_f16; A AND B
// fragments straight from global f32 (+RTN casts) -- no B LDS at all.
// Consumers: r14-validated 128-step register chain (explicit S8 expansion,
// hvA/hvB float[32] pair) + r16 med3 softmin. Spill risk retired by the
// light MFMA producer (VGPR 76 in r18 vs 84 ceiling).
// ---------------------------------------------------------------------------
__global__ __launch_bounds__(768, 3) void sdtw_kernel(const float* __restrict__ data,
                                                      const int* __restrict__ lens,
                                                      float* __restrict__ dist) {
  __shared__ __align__(16) __half DtH[2][NWAVE][64 * DRS];   // 107520 B (D*C2, fp16)
  __shared__ __align__(16) float  sqA[LQ];                   // 1536 B
  __shared__ __align__(16) float  sqB[LQ];                   // 1536 B
  __shared__ __align__(16) float  bnd[NWAVE][2][68];         // 3264 B (~114 KB total)

  const int p_id = blockIdx.x;
  const int wwin = p_id / PERW;
  const int o = p_id - wwin * PERW;
  const int aRow = wwin * STEPW;
  const int bRow = aRow + 1 + o;
  const int la = lens[aRow];
  const int lb = lens[bRow];
  const int tid = threadIdx.x;
  const int w = tid >> 6;        // 0..11
  const int lane = tid & 63;

  const float* __restrict__ A  = data + (size_t)aRow * LQ * DF;
  const float* __restrict__ Bp = data + (size_t)bRow * LQ * DF;

  // ---- sqA (threads 0..383) / sqB (threads 384..767) from global ----
  {
    const float* src = (tid < LQ) ? (A + (size_t)tid * DF) : (Bp + (size_t)(tid - LQ) * DF);
    const float4* S4 = (const float4*)src;
    float s = 0.f;
#pragma unroll
    for (int k = 0; k < 16; ++k) {
      float4 v = S4[k];
      s = fmaf(v.x, v.x, s); s = fmaf(v.y, v.y, s);
      s = fmaf(v.z, v.z, s); s = fmaf(v.w, v.w, s);
    }
    if (tid < LQ) sqA[tid] = s; else sqB[tid - LQ] = s;
  }
  __syncthreads();

  // extraction target: R[la][lb] at DP wave wt, lane it, panel pt (PW=64)
  const int wt = (la - 1) >> 6;
  const int it = (la - 1) & 63;
  const int pt = (lb - 1) >> 6;
  const int tstar = it + ((lb - 1) & 63);
  const int rstar2 = wt + pt + 1;               // consumer round index
  const float scale = L2C / (float)(la + lb);

  if (w < NWAVE) {
    // =====================  GEMM (producer) waves: MFMA  ===================
    const int g = w;
    const int colL = lane & 31;                 // M-row / N-col within tile
    const int kh = (lane >> 5) * 8;             // K sub-offset (0 or 8)
    const int rq = 4 * (lane >> 5);             // row offset for C/D mapping
    const bool gActive = (64 * g < la);

    for (int rr = 0; rr < NROUND2; ++rr) {
      __syncthreads();
      const int p = rr - g;
      if ((unsigned)p < (unsigned)NPANEL && gActive && (64 * p < lb)) {
        __half* DtW = &DtH[rr & 1][g][0];
#pragma unroll
        for (int mt = 0; mt < 2; ++mt) {
          // ---- A fragments for this 32-row band (reused by both col-tiles) --
          const float* arow = A + (size_t)(64 * g + 32 * mt + colL) * DF + kh;
          h16x8 afr[4];
#pragma unroll
          for (int ks = 0; ks < 4; ++ks) {
            float4 a0 = *(const float4*)(arow + ks * 16);
            float4 a1 = *(const float4*)(arow + ks * 16 + 4);
            h16x8 af;
            af[0] = (_Float16)a0.x; af[1] = (_Float16)a0.y;
            af[2] = (_Float16)a0.z; af[3] = (_Float16)a0.w;
            af[4] = (_Float16)a1.x; af[5] = (_Float16)a1.y;
            af[6] = (_Float16)a1.z; af[7] = (_Float16)a1.w;
            afr[ks] = af;
          }
#pragma unroll
          for (int ct = 0; ct < 2; ++ct) {
            const float* brow = Bp + (size_t)(PW * p + 32 * ct + colL) * DF + kh;
            f32x16 acc;
#pragma unroll
            for (int ii = 0; ii < 16; ++ii) acc[ii] = 0.f;
#pragma unroll
            for (int ks = 0; ks < 4; ++ks) {
              float4 b0 = *(const float4*)(brow + ks * 16);
              float4 b1 = *(const float4*)(brow + ks * 16 + 4);
              h16x8 bf;
              bf[0] = (_Float16)b0.x; bf[1] = (_Float16)b0.y;
              bf[2] = (_Float16)b0.z; bf[3] = (_Float16)b0.w;
              bf[4] = (_Float16)b1.x; bf[5] = (_Float16)b1.y;
              bf[6] = (_Float16)b1.z; bf[7] = (_Float16)b1.w;
              acc = __builtin_amdgcn_mfma_f32_32x32x16_f16(afr[ks], bf, acc, 0, 0, 0);
            }
            // epilogue: D' = (sqA[row] + sqB[col] - 2*dot)*C2 -> fp16 store
            float sb = sqB[PW * p + 32 * ct + colL];
#pragma unroll
            for (int qq = 0; qq < 4; ++qq) {
              float4 sa = *(const float4*)&sqA[64 * g + 32 * mt + 8 * qq + rq];
              float sas[4] = {sa.x, sa.y, sa.z, sa.w};
#pragma unroll
              for (int ii = 0; ii < 4; ++ii) {
                int reg = qq * 4 + ii;
                int row = 32 * mt + 8 * qq + rq + ii;
                float dv = (sas[ii] + sb - 2.f * acc[reg]) * C2;
                DtW[row * DRS + 32 * ct + colL] = __float2half(dv);
              }
            }
          }
        }
      }
    }
  } else {
    // =====================  DP (consumer) waves  ===========================
    const int d = w - NWAVE;                    // 0..5, owns rows 64d+1..64d+64
    const bool dActive = (64 * d < la);
    const int dn = (d + 1 < NWAVE) ? (d + 1) : 0;
    float leftR = BIGS;

    for (int rr = 0; rr < NROUND2; ++rr) {
      __syncthreads();
      const int p = rr - 1 - d;
      if ((unsigned)p < (unsigned)NPANEL && dActive && (64 * p < lb)) {
        const __half* DtW = &DtH[(rr - 1) & 1][d][0];

        float* bndR = &bnd[d][rr & 1][0];
        float* bndW = &bnd[dn][(rr + 1) & 1][0];
        const bool wr63 = (lane == 63) && (d + 1 < NWAVE) && (64 * (d + 1) < la);
        if (wr63) bndW[0] = leftR;

        // ---- preload D row rotated, as TWO float[32] (literal indices) -----
        const ushort* rowb = (const ushort*)&DtW[lane * DRS];
        float hvA[32], hvB[32];
#pragma unroll
        for (int pp = 0; pp < 32; ++pp) {
          int src = (pp - lane) & 31;
          hvA[pp] = __half2float(__ushort_as_half(rowb[src]));
          hvB[pp] = __half2float(__ushort_as_half(rowb[32 + src]));
        }

        // ---- boundary row (65 floats) into regs ----------------------------
        float vbnd = BIGS, b64v = BIGS;
        if (d > 0) { vbnd = bndR[lane]; b64v = bndR[64]; }

        float cur = leftR;
        float extv = 0.f;
        float s2;
        {
          float fix0 = (d == 0) ? ((p == 0) ? 0.f : BIGS) : rdlane(vbnd, 0);
          s2 = (lane == 0) ? fix0 : cur;
        }
        const bool extRound = (d == wt) && (rr == rstar2);

#define STEP(T) do {                                                        \
        float s1 = wshr1f(cur);                                             \
        if ((T) < 64) {                                                     \
          float bup = ((T) < 63) ? rdlane(vbnd, (T) + 1) : b64v;            \
          bup = (d == 0) ? BIGS : bup;                                      \
          s1 = (lane == 0) ? bup : s1;                                      \
        }                                                                   \
        int jl = (T) - lane;                                                \
        float dv = ((unsigned)jl < 32u) ? hvA[(T) & 31] : hvB[(T) & 31];    \
        float m  = fminf(s2, fminf(s1, cur));            /* v_min3 */       \
        float md = __builtin_amdgcn_fmed3f(s2, s1, cur); /* v_med3 */       \
        float mx = fmaxf(s2, fmaxf(s1, cur));            /* v_max3 */       \
        float e = 1.0f + fexp2(m - md) + fexp2(m - mx);                     \
        float val = dv + m - flog2(e);                                      \
        s2 = s1;                                                            \
        if (extRound && tstar == (T) && lane == it) extv = val;             \
        if ((unsigned)jl < 64u) {                                           \
          cur = val;                                                        \
          if ((T) >= 63) { if (wr63) bndW[jl + 1] = val; }                  \
        }                                                                   \
      } while (0)

#define S8(T) STEP((T)); STEP((T)+1); STEP((T)+2); STEP((T)+3); \
              STEP((T)+4); STEP((T)+5); STEP((T)+6); STEP((T)+7);

        S8(0)   S8(8)   S8(16)  S8(24)
        S8(32)  S8(40)  S8(48)  S8(56)
        S8(64)  S8(72)  S8(80)  S8(88)
        S8(96)  S8(104) S8(112) S8(120)
#undef S8
#undef STEP
        if (extRound && lane == it) dist[p_id] = extv * scale;
        leftR = cur;
      }
    }
  }
}

// ---------------------------------------------------------------------------
// Loss reduction over 16 windows (validated rounds 1-18).
// ---------------------------------------------------------------------------
__device__ __forceinline__ float median5(const float* v) {
#pragma unroll
  for (int i = 0; i < 5; ++i) {
    int c = 0;
#pragma unroll
    for (int j = 0; j < 5; ++j)
      c += (v[j] < v[i]) || ((v[j] == v[i]) && (j < i));
    if (c == 2) return v[i];
  }
  return v[0];
}

__global__ void loss_kernel(const float* __restrict__ dist, float* __restrict__ out) {
  __shared__ float acc[NWIN];
  const int w = threadIdx.x;
  if (w < NWIN) {
    float dg[5], dn[10];
#pragma unroll
    for (int g = 0; g < 5; ++g)  dg[g] = dist[w * PERW + g];
#pragma unroll
    for (int n = 0; n < 10; ++n) dn[n] = dist[w * PERW + 5 + n];

    float lk = 0.f; int nz = 0;
#pragma unroll
    for (int g = 0; g < 5; ++g)
#pragma unroll
      for (int n = 0; n < 10; ++n) {
        float t = dg[g] + 1.0f - dn[n];
        if (t > 0.f) { lk += t; ++nz; }
      }
    float lv = lk / (1.0f + (float)nz);

    float sp = 0.f;
#pragma unroll
    for (int g = 0; g < 5; ++g) sp += dg[g];
    float only_pos = sp * (0.01f / 5.0f);

    float mg = median5(dg);
    float ms = median5(dn);

    int err = 0;
#pragma unroll
    for (int g = 0; g < 5; ++g) {
      err += ((dg[g] < mg) && (dn[g] < mg));
      err += ((dg[g] > ms) && (dn[g] > ms));
      err += ((dg[g] < mg) && (dn[5 + g] < mg));
      err += ((dg[g] > ms) && (dn[5 + g] > ms));
    }
    float offset = (float)err * (1.0f / 50.0f);

    acc[w] = lv + only_pos + offset;
  }
  __syncthreads();
  if (w == 0) {
    float s = 0.f;
#pragma unroll
    for (int i = 0; i < NWIN; ++i) s += acc[i];
    out[0] = s / (float)NWIN;
  }
}

// ---------------------------------------------------------------------------
extern "C" void kernel_launch(void* const* d_in, const int* in_sizes, int n_in,
                              void* d_out, int out_size, void* d_ws, size_t ws_size,
                              hipStream_t stream) {
  const float* data = (const float*)d_in[0];
  const int* lens   = (const int*)d_in[1];
  float* dist = (float*)d_ws;

  sdtw_kernel<<<NPAIR, 768, 0, stream>>>(data, lens, dist);
  loss_kernel<<<1, 64, 0, stream>>>(dist, (float*)d_out);
}

// Round 20
// 133.109 us; speedup vs baseline: 1.3792x; 1.3792x over previous
//
#include <hip/hip_runtime.h>
#include <hip/hip_fp16.h>

#define LQ 384
#define DF 64
#define NWIN 16
#define PERW 15      // NG + NF
#define STEPW 16     // 1 + NG + NF
#define NPAIR 240    // NWIN * PERW
#define NWAVE 6      // row-slabs (producer waves and consumer waves each)
#define PW 32        // panel width (cols per round)
#define NPANEL 12    // 384 / PW
#define NROUND2 18   // NPANEL + NWAVE - 1 + 1 (producer lead)
#define BSTH 72      // fp16 B LDS row stride (halfs); 144 B = 16B-aligned rows
#define DRS 36       // fp16 D-tile ROW stride (halfs); 72 B, 8B-aligned
#define C2  0.28853900817779268f   // 1/(5*ln2)  (pre-scale: R' = R*C2)
#define L2C 3.4657359027997265f    // 5*ln2      (unscale at extraction)
#define BIGS (1e9f * C2)           // BIG in scaled domain

typedef _Float16 h16x8 __attribute__((ext_vector_type(8)));
typedef float    f32x16 __attribute__((ext_vector_type(16)));

__device__ __forceinline__ float fexp2(float x) { return __builtin_amdgcn_exp2f(x); }
__device__ __forceinline__ float flog2(float x) { return __builtin_amdgcn_logf(x); }

// wave_shr:1 -- lane l gets lane l-1's value (VALU pipe). lane0 keeps own (fixed up).
__device__ __forceinline__ float wshr1f(float x) {
  int xi = __float_as_int(x);
  return __int_as_float(__builtin_amdgcn_update_dpp(xi, xi, 0x138, 0xF, 0xF, false));
}
__device__ __forceinline__ float rdlane(float v, int l) {
  return __int_as_float(__builtin_amdgcn_readlane(__float_as_int(v), l));
}

// ---------------------------------------------------------------------------
// Producer-consumer soft-DTW (r18-validated, 134us / absmax 0.0).
// Producers on MFMA (v_mfma_f32_32x32x16_f16): B fragments from fp16 LDS
// (1 ds_read_b128 each, HOISTED out of the mt loop -- they depend only on
// panel/ks, not the row-tile), A fragments from global f32 + RTN casts.
// Consumers: pure-register 96-step DP chain, med3 softmin identity.
// ---------------------------------------------------------------------------
__global__ __launch_bounds__(768, 3) void sdtw_kernel(const float* __restrict__ data,
                                                      const int* __restrict__ lens,
                                                      float* __restrict__ dist) {
  __shared__ __align__(16) __half BshH[LQ * BSTH];           // 55296 B (B in fp16)
  __shared__ __align__(16) __half DtH[2][NWAVE][64 * DRS];   // 55296 B (D*C2, fp16)
  __shared__ __align__(16) float  sqA[LQ];                   // 1536 B
  __shared__ __align__(16) float  sqB[LQ];                   // 1536 B
  __shared__ __align__(16) float  bnd[NWAVE][2][36];         // 1728 B  (115392 total)

  const int p_id = blockIdx.x;
  const int wwin = p_id / PERW;
  const int o = p_id - wwin * PERW;
  const int aRow = wwin * STEPW;
  const int bRow = aRow + 1 + o;
  const int la = lens[aRow];
  const int lb = lens[bRow];
  const int tid = threadIdx.x;
  const int w = tid >> 6;        // 0..11
  const int lane = tid & 63;

  const float* __restrict__ A  = data + (size_t)aRow * LQ * DF;
  const float* __restrict__ Bp = data + (size_t)bRow * LQ * DF;

  // ---- stage B (fp16) into LDS; sqA/sqB from fp32 global ----
  {
    const float4* B4 = (const float4*)Bp;
    for (int q = tid; q < LQ * 16; q += 768) {
      float4 v = B4[q];
      int row = q >> 4, c4 = (q & 15) << 2;
      uint u0 = __half_as_ushort(__float2half(v.x)) |
                ((uint)__half_as_ushort(__float2half(v.y)) << 16);
      uint u1 = __half_as_ushort(__float2half(v.z)) |
                ((uint)__half_as_ushort(__float2half(v.w)) << 16);
      uint2 qq; qq.x = u0; qq.y = u1;
      *(uint2*)&BshH[row * BSTH + c4] = qq;     // 8B-aligned
    }
  }
  {
    const float* src = (tid < LQ) ? (A + (size_t)tid * DF) : (Bp + (size_t)(tid - LQ) * DF);
    const float4* S4 = (const float4*)src;
    float s = 0.f;
#pragma unroll
    for (int k = 0; k < 16; ++k) {
      float4 v = S4[k];
      s = fmaf(v.x, v.x, s); s = fmaf(v.y, v.y, s);
      s = fmaf(v.z, v.z, s); s = fmaf(v.w, v.w, s);
    }
    if (tid < LQ) sqA[tid] = s; else sqB[tid - LQ] = s;
  }
  __syncthreads();

  // extraction target: R[la][lb] at DP wave wt, lane it, panel pt
  const int wt = (la - 1) >> 6;
  const int it = (la - 1) & 63;
  const int pt = (lb - 1) >> 5;
  const int tstar = it + ((lb - 1) & 31);
  const int rstar2 = wt + pt + 1;               // consumer round index
  const float scale = L2C / (float)(la + lb);

  if (w < NWAVE) {
    // =====================  GEMM (producer) waves: MFMA  ===================
    const int g = w;
    const int colL = lane & 31;                 // M-row / N-col within tile
    const int kh = (lane >> 5) * 8;             // K sub-offset (0 or 8)
    const int rq = 4 * (lane >> 5);             // row offset for C/D mapping
    const bool gActive = (64 * g < la);

    for (int rr = 0; rr < NROUND2; ++rr) {
      __syncthreads();
      const int p = rr - g;
      if ((unsigned)p < (unsigned)NPANEL && gActive && (32 * p < lb)) {
        __half* DtW = &DtH[rr & 1][g][0];
        float sb = sqB[PW * p + colL];
        // ---- B fragments: depend only on (p, colL, ks) -> load ONCE -------
        h16x8 bfr[4];
#pragma unroll
        for (int ks = 0; ks < 4; ++ks)
          bfr[ks] = *(const h16x8*)&BshH[(size_t)(PW * p + colL) * BSTH + ks * 16 + kh];
#pragma unroll
        for (int mt = 0; mt < 2; ++mt) {
          const float* arow = A + (size_t)(64 * g + 32 * mt + colL) * DF + kh;
          f32x16 acc;
#pragma unroll
          for (int ii = 0; ii < 16; ++ii) acc[ii] = 0.f;
#pragma unroll
          for (int ks = 0; ks < 4; ++ks) {
            float4 a0 = *(const float4*)(arow + ks * 16);
            float4 a1 = *(const float4*)(arow + ks * 16 + 4);
            h16x8 af;
            af[0] = (_Float16)a0.x; af[1] = (_Float16)a0.y;
            af[2] = (_Float16)a0.z; af[3] = (_Float16)a0.w;
            af[4] = (_Float16)a1.x; af[5] = (_Float16)a1.y;
            af[6] = (_Float16)a1.z; af[7] = (_Float16)a1.w;
            acc = __builtin_amdgcn_mfma_f32_32x32x16_f16(af, bfr[ks], acc, 0, 0, 0);
          }
          // epilogue: D' = (sqA[row] + sqB[col] - 2*dot)*C2 -> fp16 RTN store
#pragma unroll
          for (int qq = 0; qq < 4; ++qq) {
            float4 sa = *(const float4*)&sqA[64 * g + 32 * mt + 8 * qq + rq];
            float sas[4] = {sa.x, sa.y, sa.z, sa.w};
#pragma unroll
            for (int ii = 0; ii < 4; ++ii) {
              int reg = qq * 4 + ii;
              int row = 32 * mt + 8 * qq + rq + ii;
              float dv = (sas[ii] + sb - 2.f * acc[reg]) * C2;
              DtW[row * DRS + colL] = __float2half(dv);
            }
          }
        }
      }
    }
  } else {
    // =====================  DP (consumer) waves (r16/r18-validated)  =======
    const int d = w - NWAVE;                    // 0..5, owns rows 64d+1..64d+64
    const bool dActive = (64 * d < la);
    const int dn = (d + 1 < NWAVE) ? (d + 1) : 0;
    const int l5 = lane & 31;
    float leftR = BIGS;

    for (int rr = 0; rr < NROUND2; ++rr) {
      __syncthreads();
      const int p = rr - 1 - d;
      if ((unsigned)p < (unsigned)NPANEL && dActive && (32 * p < lb)) {
        const __half* DtW = &DtH[(rr - 1) & 1][d][0];

        float* bndR = &bnd[d][rr & 1][0];
        float* bndW = &bnd[dn][(rr + 1) & 1][0];
        const bool wr63 = (lane == 63) && (d + 1 < NWAVE) && (64 * (d + 1) < la);
        if (wr63) bndW[0] = leftR;

        // ---- preload D row, rotated, as FLOAT --------------------------
        const __half* baseA = DtW + (lane * DRS - l5);
        const __half* baseB = baseA + 32;
        float hv[32];
#pragma unroll
        for (int pp = 0; pp < 32; ++pp)
          hv[pp] = __half2float((pp < l5) ? baseB[pp] : baseA[pp]);

        // ---- preload boundary row into one VGPR per lane ----------------
        float vbnd = BIGS;
        if (d > 0 && lane < 36) vbnd = bndR[lane];

        float cur = leftR;
        float extv = 0.f;
        float s2;
        {
          float fix0 = (d == 0) ? ((p == 0) ? 0.f : BIGS) : rdlane(vbnd, 0);
          s2 = (lane == 0) ? fix0 : cur;
        }
        const bool extRound = (d == wt) && (rr == rstar2);

#define STEP(T) do {                                                        \
        float s1 = wshr1f(cur);                                             \
        if ((T) < 32) {                                                     \
          float bup = rdlane(vbnd, (T) + 1);                                \
          s1 = (lane == 0) ? bup : s1;                                      \
        }                                                                   \
        float dv = hv[(T) & 31];                                            \
        float m  = fminf(s2, fminf(s1, cur));            /* v_min3 */       \
        float md = __builtin_amdgcn_fmed3f(s2, s1, cur); /* v_med3 */       \
        float mx = fmaxf(s2, fmaxf(s1, cur));            /* v_max3 */       \
        float e = 1.0f + fexp2(m - md) + fexp2(m - mx);                     \
        float val = dv + m - flog2(e);                                      \
        s2 = s1;                                                            \
        if (extRound && tstar == (T) && lane == it) extv = val;             \
        int jl = (T) - lane;                                                \
        if ((unsigned)jl < 32u) {                                           \
          cur = val;                                                        \
          if ((T) >= 63) { if (wr63) bndW[jl + 1] = val; }                  \
        }                                                                   \
      } while (0)

#pragma unroll
        for (int T = 0; T < 96; ++T) STEP(T);
#undef STEP
        if (extRound && lane == it) dist[p_id] = extv * scale;
        leftR = cur;
      }
    }
  }
}

// ---------------------------------------------------------------------------
// Loss reduction over 16 windows (validated rounds 1-19).
// ---------------------------------------------------------------------------
__device__ __forceinline__ float median5(const float* v) {
#pragma unroll
  for (int i = 0; i < 5; ++i) {
    int c = 0;
#pragma unroll
    for (int j = 0; j < 5; ++j)
      c += (v[j] < v[i]) || ((v[j] == v[i]) && (j < i));
    if (c == 2) return v[i];
  }
  return v[0];
}

__global__ void loss_kernel(const float* __restrict__ dist, float* __restrict__ out) {
  __shared__ float acc[NWIN];
  const int w = threadIdx.x;
  if (w < NWIN) {
    float dg[5], dn[10];
#pragma unroll
    for (int g = 0; g < 5; ++g)  dg[g] = dist[w * PERW + g];
#pragma unroll
    for (int n = 0; n < 10; ++n) dn[n] = dist[w * PERW + 5 + n];

    float lk = 0.f; int nz = 0;
#pragma unroll
    for (int g = 0; g < 5; ++g)
#pragma unroll
      for (int n = 0; n < 10; ++n) {
        float t = dg[g] + 1.0f - dn[n];
        if (t > 0.f) { lk += t; ++nz; }
      }
    float lv = lk / (1.0f + (float)nz);

    float sp = 0.f;
#pragma unroll
    for (int g = 0; g < 5; ++g) sp += dg[g];
    float only_pos = sp * (0.01f / 5.0f);

    float mg = median5(dg);
    float ms = median5(dn);

    int err = 0;
#pragma unroll
    for (int g = 0; g < 5; ++g) {
      err += ((dg[g] < mg) && (dn[g] < mg));
      err += ((dg[g] > ms) && (dn[g] > ms));
      err += ((dg[g] < mg) && (dn[5 + g] < mg));
      err += ((dg[g] > ms) && (dn[5 + g] > ms));
    }
    float offset = (float)err * (1.0f / 50.0f);

    acc[w] = lv + only_pos + offset;
  }
  __syncthreads();
  if (w == 0) {
    float s = 0.f;
#pragma unroll
    for (int i = 0; i < NWIN; ++i) s += acc[i];
    out[0] = s / (float)NWIN;
  }
}

// ---------------------------------------------------------------------------
extern "C" void kernel_launch(void* const* d_in, const int* in_sizes, int n_in,
                              void* d_out, int out_size, void* d_ws, size_t ws_size,
                              hipStream_t stream) {
  const float* data = (const float*)d_in[0];
  const int* lens   = (const int*)d_in[1];
  float* dist = (float*)d_ws;

  sdtw_kernel<<<NPAIR, 768, 0, stream>>>(data, lens, dist);
  loss_kernel<<<1, 64, 0, stream>>>(dist, (float*)d_out);
}

// Round 21
// 125.854 us; speedup vs baseline: 1.4587x; 1.0577x over previous
//
#include <hip/hip_runtime.h>
#include <hip/hip_fp16.h>

#define LQ 384
#define DF 64
#define NWIN 16
#define PERW 15      // NG + NF
#define STEPW 16     // 1 + NG + NF
#define NPAIR 240    // NWIN * PERW
#define NWAVE 6      // row-slabs (producer waves and consumer waves each)
#define PW 32        // D panel width (cols per production)
#define NPANEL 12    // 384 / PW
#define NRND 30      // continuous-flow rounds: 14 local + 3*5 skew + 1
#define BSTH 72      // fp16 B LDS row stride (halfs); 144 B = 16B-aligned rows
#define DRS 33       // fp16 D row stride (halfs); odd -> bank-spread u16 reads
#define C2  0.28853900817779268f   // 1/(5*ln2)  (pre-scale: R' = R*C2)
#define L2C 3.4657359027997265f    // 5*ln2      (unscale at extraction)
#define BIGS (1e9f * C2)           // BIG in scaled domain

typedef _Float16 h16x8 __attribute__((ext_vector_type(8)));
typedef float    f32x16 __attribute__((ext_vector_type(16)));

__device__ __forceinline__ float fexp2(float x) { return __builtin_amdgcn_exp2f(x); }
__device__ __forceinline__ float flog2(float x) { return __builtin_amdgcn_logf(x); }

// wave_shr:1 -- lane l gets lane l-1's value (VALU pipe). lane0 keeps own (fixed up).
__device__ __forceinline__ float wshr1f(float x) {
  int xi = __float_as_int(x);
  return __int_as_float(__builtin_amdgcn_update_dpp(xi, xi, 0x138, 0xF, 0xF, false));
}
__device__ __forceinline__ float rdlane(float v, int l) {
  return __int_as_float(__builtin_amdgcn_readlane(__float_as_int(v), l));
}

// ---------------------------------------------------------------------------
// Continuous-flow soft-DTW. Consumers run ONE uninterrupted anti-diagonal
// wavefront over all 384 cols (col = T - lane; cur/s2 persist across rounds)
// -- all 64 lanes active in steady state, 960 wall steps vs 1728 panelized.
// Producers (r20-validated MFMA) stay 1+ panels ahead into a mod-4 D ring;
// slab boundaries flow through a mod-3 LDS ring with 3-round skew.
// ---------------------------------------------------------------------------
__global__ __launch_bounds__(768, 3) void sdtw_kernel(const float* __restrict__ data,
                                                      const int* __restrict__ lens,
                                                      float* __restrict__ dist) {
  __shared__ __align__(16) __half BshH[LQ * BSTH];           // 55296 B
  __shared__ __align__(16) __half DtH[4][NWAVE][64 * DRS];   // 101376 B (D*C2 fp16)
  __shared__ __align__(16) float  sqA[LQ];                   // 1536 B
  __shared__ __align__(16) float  sqB[LQ];                   // 1536 B
  __shared__ __align__(16) float  ring[NWAVE][3][32];        // 2304 B (162048 total)

  const int p_id = blockIdx.x;
  const int wwin = p_id / PERW;
  const int o = p_id - wwin * PERW;
  const int aRow = wwin * STEPW;
  const int bRow = aRow + 1 + o;
  const int la = lens[aRow];
  const int lb = lens[bRow];
  const int tid = threadIdx.x;
  const int w = tid >> 6;        // 0..11
  const int lane = tid & 63;

  const float* __restrict__ A  = data + (size_t)aRow * LQ * DF;
  const float* __restrict__ Bp = data + (size_t)bRow * LQ * DF;

  // ---- stage B (fp16) into LDS; sqA/sqB from fp32 global ----
  {
    const float4* B4 = (const float4*)Bp;
    for (int q = tid; q < LQ * 16; q += 768) {
      float4 v = B4[q];
      int row = q >> 4, c4 = (q & 15) << 2;
      uint u0 = __half_as_ushort(__float2half(v.x)) |
                ((uint)__half_as_ushort(__float2half(v.y)) << 16);
      uint u1 = __half_as_ushort(__float2half(v.z)) |
                ((uint)__half_as_ushort(__float2half(v.w)) << 16);
      uint2 qq; qq.x = u0; qq.y = u1;
      *(uint2*)&BshH[row * BSTH + c4] = qq;
    }
  }
  {
    const float* src = (tid < LQ) ? (A + (size_t)tid * DF) : (Bp + (size_t)(tid - LQ) * DF);
    const float4* S4 = (const float4*)src;
    float s = 0.f;
#pragma unroll
    for (int k = 0; k < 16; ++k) {
      float4 v = S4[k];
      s = fmaf(v.x, v.x, s); s = fmaf(v.y, v.y, s);
      s = fmaf(v.z, v.z, s); s = fmaf(v.w, v.w, s);
    }
    if (tid < LQ) sqA[tid] = s; else sqB[tid - LQ] = s;
  }
  __syncthreads();

  // extraction: R[la][lb] at wave wt, lane it, continuous step T* = (lb-1)+it
  const int wt = (la - 1) >> 6;
  const int it = (la - 1) & 63;
  const int Tstar = (lb - 1) + it;
  const int qstar = Tstar >> 5;
  const int t32 = Tstar & 31;
  const float scale = L2C / (float)(la + lb);

  if (w < NWAVE) {
    // =====================  GEMM (producer) waves: MFMA  ===================
    const int g = w;
    const int colL = lane & 31;
    const int kh = (lane >> 5) * 8;
    const int rq = 4 * (lane >> 5);
    const bool gActive = (64 * g < la);

    for (int rr = 0; rr < NRND; ++rr) {
      __syncthreads();
      const int p = rr - 3 * g;          // producer writes panel p this round
      if ((unsigned)p < (unsigned)NPANEL && gActive && (32 * p < lb)) {
        __half* DtW = &DtH[p & 3][g][0];
        float sb = sqB[PW * p + colL];
        h16x8 bfr[4];
#pragma unroll
        for (int ks = 0; ks < 4; ++ks)
          bfr[ks] = *(const h16x8*)&BshH[(size_t)(PW * p + colL) * BSTH + ks * 16 + kh];
#pragma unroll
        for (int mt = 0; mt < 2; ++mt) {
          const float* arow = A + (size_t)(64 * g + 32 * mt + colL) * DF + kh;
          f32x16 acc;
#pragma unroll
          for (int ii = 0; ii < 16; ++ii) acc[ii] = 0.f;
#pragma unroll
          for (int ks = 0; ks < 4; ++ks) {
            float4 a0 = *(const float4*)(arow + ks * 16);
            float4 a1 = *(const float4*)(arow + ks * 16 + 4);
            h16x8 af;
            af[0] = (_Float16)a0.x; af[1] = (_Float16)a0.y;
            af[2] = (_Float16)a0.z; af[3] = (_Float16)a0.w;
            af[4] = (_Float16)a1.x; af[5] = (_Float16)a1.y;
            af[6] = (_Float16)a1.z; af[7] = (_Float16)a1.w;
            acc = __builtin_amdgcn_mfma_f32_32x32x16_f16(af, bfr[ks], acc, 0, 0, 0);
          }
#pragma unroll
          for (int qq = 0; qq < 4; ++qq) {
            float4 sa = *(const float4*)&sqA[64 * g + 32 * mt + 8 * qq + rq];
            float sas[4] = {sa.x, sa.y, sa.z, sa.w};
#pragma unroll
            for (int ii = 0; ii < 4; ++ii) {
              int reg = qq * 4 + ii;
              int row = 32 * mt + 8 * qq + rq + ii;
              float dv = (sas[ii] + sb - 2.f * acc[reg]) * C2;
              DtW[row * DRS + colL] = __float2half(dv);
            }
          }
        }
      }
    }
  } else {
    // =====================  DP (consumer) waves: continuous flow  ==========
    const int d = w - NWAVE;            // slab: rows 64d+1..64d+64 (lane = row)
    const bool dActive = (64 * d < la);
    const int dn = (d + 1 < NWAVE) ? (d + 1) : 0;
    const bool wr63 = (lane == 63) && (d + 1 < NWAVE) && (64 * (d + 1) < la);
    const bool extWave = (d == wt);

    float cur = BIGS;                   // R[row][col-boundary] persists across rounds
    float s2  = (d == 0 && lane == 0) ? 0.f : BIGS;   // diag seed: R[0][0]=0
    float extv = 0.f;

    for (int rr = 0; rr < NRND; ++rr) {
      __syncthreads();
      const int q = rr - 3 * d - 1;     // local 32-step window index, 0..13
      if ((unsigned)q < 14u && dActive) {
        // ---- preload 32 D values (rotated two-pointer, r13 pattern) -------
        const int c0 = 32 * q - lane;   // col of hv[0]
        const int pnlA = c0 >> 5;       // arithmetic shift (c0 may be <0)
        const int offA = c0 & 31;
        const int k = 32 - offA;        // t<k -> panel pnlA, else pnlA+1
        int pAc = pnlA < 0 ? 0 : (pnlA > 11 ? 11 : pnlA);
        int pBi = pnlA + 1;
        int pBc = pBi < 0 ? 0 : (pBi > 11 ? 11 : pBi);
        const ushort* bA = (const ushort*)&DtH[pAc & 3][d][lane * DRS + offA];
        const ushort* bB = (const ushort*)&DtH[pBc & 3][d][lane * DRS] - k;
        float hv[32];
#pragma unroll
        for (int t = 0; t < 32; ++t) {
          const ushort* ptr = (t < k) ? (bA + t) : (bB + t);
          hv[t] = __half2float(__ushort_as_half(*ptr));
        }
        // ---- boundary ring: read panel q; write bases for panels q-2,q-1 --
        float vbnd = BIGS;
        if (d > 0) vbnd = ring[d][q % 3][lane & 31];
        float* pW1 = &ring[dn][(q + 1) % 3][0];   // == (q-2)%3, slots t+1
        float* pW2 = &ring[dn][(q + 2) % 3][0];   // == (q-1)%3, slot 0
        const int cb = 32 * q;
        const bool ext = extWave && (q == qstar);
        const bool steady = (q >= 2) && (q <= 11);

#define STEPX(T, EXT, GUARD) do {                                           \
        float s1 = wshr1f(cur);                                             \
        float bup = rdlane(vbnd, (T));                                      \
        s1 = (lane == 0) ? bup : s1;                                        \
        float dv = hv[(T)];                                                 \
        float m  = fminf(s2, fminf(s1, cur));                               \
        float md = __builtin_amdgcn_fmed3f(s2, s1, cur);                    \
        float mx = fmaxf(s2, fmaxf(s1, cur));                               \
        float e = 1.0f + fexp2(m - md) + fexp2(m - mx);                     \
        float val = dv + m - flog2(e);                                      \
        s2 = s1;                                                            \
        if (EXT) { if ((T) == t32 && lane == it) extv = val; }              \
        if (GUARD) {                                                        \
          if ((unsigned)(cb + (T) - lane) < 384u) cur = val;                \
          if (wr63 && (unsigned)(cb + (T) - 63) < 384u) {                   \
            if ((T) < 31) pW1[(T) + 1] = val; else pW2[0] = val;            \
          }                                                                 \
        } else {                                                            \
          cur = val;                                                        \
          if (wr63) { if ((T) < 31) pW1[(T) + 1] = val; else pW2[0] = val; }\
        }                                                                   \
      } while (0)

#define LOOP32(E, G) _Pragma("unroll") for (int T = 0; T < 32; ++T) STEPX(T, E, G);

        if (steady) {
          if (ext) { LOOP32(1, 0) } else { LOOP32(0, 0) }
        } else {
          if (ext) { LOOP32(1, 1) } else { LOOP32(0, 1) }
        }
#undef LOOP32
#undef STEPX
        if (ext && lane == it) dist[p_id] = extv * scale;
      }
    }
  }
}

// ---------------------------------------------------------------------------
// Loss reduction over 16 windows (validated rounds 1-20).
// ---------------------------------------------------------------------------
__device__ __forceinline__ float median5(const float* v) {
#pragma unroll
  for (int i = 0; i < 5; ++i) {
    int c = 0;
#pragma unroll
    for (int j = 0; j < 5; ++j)
      c += (v[j] < v[i]) || ((v[j] == v[i]) && (j < i));
    if (c == 2) return v[i];
  }
  return v[0];
}

__global__ void loss_kernel(const float* __restrict__ dist, float* __restrict__ out) {
  __shared__ float acc[NWIN];
  const int w = threadIdx.x;
  if (w < NWIN) {
    float dg[5], dn[10];
#pragma unroll
    for (int g = 0; g < 5; ++g)  dg[g] = dist[w * PERW + g];
#pragma unroll
    for (int n = 0; n < 10; ++n) dn[n] = dist[w * PERW + 5 + n];

    float lk = 0.f; int nz = 0;
#pragma unroll
    for (int g = 0; g < 5; ++g)
#pragma unroll
      for (int n = 0; n < 10; ++n) {
        float t = dg[g] + 1.0f - dn[n];
        if (t > 0.f) { lk += t; ++nz; }
      }
    float lv = lk / (1.0f + (float)nz);

    float sp = 0.f;
#pragma unroll
    for (int g = 0; g < 5; ++g) sp += dg[g];
    float only_pos = sp * (0.01f / 5.0f);

    float mg = median5(dg);
    float ms = median5(dn);

    int err = 0;
#pragma unroll
    for (int g = 0; g < 5; ++g) {
      err += ((dg[g] < mg) && (dn[g] < mg));
      err += ((dg[g] > ms) && (dn[g] > ms));
      err += ((dg[g] < mg) && (dn[5 + g] < mg));
      err += ((dg[g] > ms) && (dn[5 + g] > ms));
    }
    float offset = (float)err * (1.0f / 50.0f);

    acc[w] = lv + only_pos + offset;
  }
  __syncthreads();
  if (w == 0) {
    float s = 0.f;
#pragma unroll
    for (int i = 0; i < NWIN; ++i) s += acc[i];
    out[0] = s / (float)NWIN;
  }
}

// ---------------------------------------------------------------------------
extern "C" void kernel_launch(void* const* d_in, const int* in_sizes, int n_in,
                              void* d_out, int out_size, void* d_ws, size_t ws_size,
                              hipStream_t stream) {
  const float* data = (const float*)d_in[0];
  const int* lens   = (const int*)d_in[1];
  float* dist = (float*)d_ws;

  sdtw_kernel<<<NPAIR, 768, 0, stream>>>(data, lens, dist);
  loss_kernel<<<1, 64, 0, stream>>>(dist, (float*)d_out);
}

// Round 22
// 102.496 us; speedup vs baseline: 1.7911x; 1.2279x over previous
//
#include <hip/hip_runtime.h>
#include <hip/hip_fp16.h>

#define LQ 384
#define DF 64
#define NWIN 16
#define PERW 15      // NG + NF
#define STEPW 16     // 1 + NG + NF
#define NPAIR 240    // NWIN * PERW
#define NWAVE 6      // row-slabs (producer waves and consumer waves each)
#define PW 32        // D panel width (cols per production)
#define NPANEL 12    // 384 / PW
#define NRND 30      // continuous-flow rounds: 14 local + 3*5 skew + 1
#define BSTH 72      // fp16 B LDS row stride (halfs); 144 B = 16B-aligned rows
#define DRS 33       // fp16 D row stride (halfs)
#define C2  0.28853900817779268f   // 1/(5*ln2)  (pre-scale: R' = R*C2)
#define L2C 3.4657359027997265f    // 5*ln2      (unscale at extraction)
#define BIGS (1e9f * C2)           // BIG in scaled domain

typedef _Float16 h16x8 __attribute__((ext_vector_type(8)));
typedef float    f32x16 __attribute__((ext_vector_type(16)));

__device__ __forceinline__ float fexp2(float x) { return __builtin_amdgcn_exp2f(x); }
__device__ __forceinline__ float flog2(float x) { return __builtin_amdgcn_logf(x); }

// wave_shr:1 -- lane l gets lane l-1's value (VALU pipe). lane0 keeps own (fixed up).
__device__ __forceinline__ float wshr1f(float x) {
  int xi = __float_as_int(x);
  return __int_as_float(__builtin_amdgcn_update_dpp(xi, xi, 0x138, 0xF, 0xF, false));
}
__device__ __forceinline__ float rdlane(float v, int l) {
  return __int_as_float(__builtin_amdgcn_readlane(__float_as_int(v), l));
}

// ---------------------------------------------------------------------------
// Continuous-flow soft-DTW (r21-validated structure). NEW: per-row rotation
// of the D panel -- col c of row r stored at position (c+r)&31 in the row.
// Consumer read position becomes exactly t (lane offsets cancel), so the
// preload hits banks at stride 66B/lane with NO rotation cancellation:
// 2 lanes/bank = conflict-free (was a 32-way conflict, 15.4M events).
// ---------------------------------------------------------------------------
__global__ __launch_bounds__(768, 3) void sdtw_kernel(const float* __restrict__ data,
                                                      const int* __restrict__ lens,
                                                      float* __restrict__ dist) {
  __shared__ __align__(16) __half BshH[LQ * BSTH];           // 55296 B
  __shared__ __align__(16) __half DtH[4][NWAVE][64 * DRS];   // 101376 B (D*C2 fp16)
  __shared__ __align__(16) float  sqA[LQ];                   // 1536 B
  __shared__ __align__(16) float  sqB[LQ];                   // 1536 B
  __shared__ __align__(16) float  ring[NWAVE][3][32];        // 2304 B (162048 total)

  const int p_id = blockIdx.x;
  const int wwin = p_id / PERW;
  const int o = p_id - wwin * PERW;
  const int aRow = wwin * STEPW;
  const int bRow = aRow + 1 + o;
  const int la = lens[aRow];
  const int lb = lens[bRow];
  const int tid = threadIdx.x;
  const int w = tid >> 6;        // 0..11
  const int lane = tid & 63;

  const float* __restrict__ A  = data + (size_t)aRow * LQ * DF;
  const float* __restrict__ Bp = data + (size_t)bRow * LQ * DF;

  // ---- stage B (fp16) into LDS; sqA/sqB from fp32 global ----
  {
    const float4* B4 = (const float4*)Bp;
    for (int q = tid; q < LQ * 16; q += 768) {
      float4 v = B4[q];
      int row = q >> 4, c4 = (q & 15) << 2;
      uint u0 = __half_as_ushort(__float2half(v.x)) |
                ((uint)__half_as_ushort(__float2half(v.y)) << 16);
      uint u1 = __half_as_ushort(__float2half(v.z)) |
                ((uint)__half_as_ushort(__float2half(v.w)) << 16);
      uint2 qq; qq.x = u0; qq.y = u1;
      *(uint2*)&BshH[row * BSTH + c4] = qq;
    }
  }
  {
    const float* src = (tid < LQ) ? (A + (size_t)tid * DF) : (Bp + (size_t)(tid - LQ) * DF);
    const float4* S4 = (const float4*)src;
    float s = 0.f;
#pragma unroll
    for (int k = 0; k < 16; ++k) {
      float4 v = S4[k];
      s = fmaf(v.x, v.x, s); s = fmaf(v.y, v.y, s);
      s = fmaf(v.z, v.z, s); s = fmaf(v.w, v.w, s);
    }
    if (tid < LQ) sqA[tid] = s; else sqB[tid - LQ] = s;
  }
  __syncthreads();

  // extraction: R[la][lb] at wave wt, lane it, continuous step T* = (lb-1)+it
  const int wt = (la - 1) >> 6;
  const int it = (la - 1) & 63;
  const int Tstar = (lb - 1) + it;
  const int qstar = Tstar >> 5;
  const int t32 = Tstar & 31;
  const float scale = L2C / (float)(la + lb);

  if (w < NWAVE) {
    // =====================  GEMM (producer) waves: MFMA  ===================
    const int g = w;
    const int colL = lane & 31;
    const int kh = (lane >> 5) * 8;
    const int rq = 4 * (lane >> 5);
    const bool gActive = (64 * g < la);

    for (int rr = 0; rr < NRND; ++rr) {
      __syncthreads();
      const int p = rr - 3 * g;          // producer writes panel p this round
      if ((unsigned)p < (unsigned)NPANEL && gActive && (32 * p < lb)) {
        __half* DtW = &DtH[p & 3][g][0];
        float sb = sqB[PW * p + colL];
        h16x8 bfr[4];
#pragma unroll
        for (int ks = 0; ks < 4; ++ks)
          bfr[ks] = *(const h16x8*)&BshH[(size_t)(PW * p + colL) * BSTH + ks * 16 + kh];
#pragma unroll
        for (int mt = 0; mt < 2; ++mt) {
          const float* arow = A + (size_t)(64 * g + 32 * mt + colL) * DF + kh;
          f32x16 acc;
#pragma unroll
          for (int ii = 0; ii < 16; ++ii) acc[ii] = 0.f;
#pragma unroll
          for (int ks = 0; ks < 4; ++ks) {
            float4 a0 = *(const float4*)(arow + ks * 16);
            float4 a1 = *(const float4*)(arow + ks * 16 + 4);
            h16x8 af;
            af[0] = (_Float16)a0.x; af[1] = (_Float16)a0.y;
            af[2] = (_Float16)a0.z; af[3] = (_Float16)a0.w;
            af[4] = (_Float16)a1.x; af[5] = (_Float16)a1.y;
            af[6] = (_Float16)a1.z; af[7] = (_Float16)a1.w;
            acc = __builtin_amdgcn_mfma_f32_32x32x16_f16(af, bfr[ks], acc, 0, 0, 0);
          }
#pragma unroll
          for (int qq = 0; qq < 4; ++qq) {
            float4 sa = *(const float4*)&sqA[64 * g + 32 * mt + 8 * qq + rq];
            float sas[4] = {sa.x, sa.y, sa.z, sa.w};
#pragma unroll
            for (int ii = 0; ii < 4; ++ii) {
              int reg = qq * 4 + ii;
              int row = 32 * mt + 8 * qq + rq + ii;
              float dv = (sas[ii] + sb - 2.f * acc[reg]) * C2;
              DtW[row * DRS + ((colL + row) & 31)] = __float2half(dv);  // rotated
            }
          }
        }
      }
    }
  } else {
    // =====================  DP (consumer) waves: continuous flow  ==========
    const int d = w - NWAVE;            // slab: rows 64d+1..64d+64 (lane = row)
    const bool dActive = (64 * d < la);
    const int dn = (d + 1 < NWAVE) ? (d + 1) : 0;
    const bool wr63 = (lane == 63) && (d + 1 < NWAVE) && (64 * (d + 1) < la);
    const bool extWave = (d == wt);

    float cur = BIGS;                   // persists across rounds
    float s2  = (d == 0 && lane == 0) ? 0.f : BIGS;   // diag seed: R[0][0]=0
    float extv = 0.f;

    for (int rr = 0; rr < NRND; ++rr) {
      __syncthreads();
      const int q = rr - 3 * d - 1;     // local 32-step window index, 0..13
      if ((unsigned)q < 14u && dActive) {
        // ---- preload 32 D values: rotated layout -> position == t ---------
        const int c0 = 32 * q - lane;
        const int pnlA = c0 >> 5;
        const int k = 32 - (c0 & 31);   // t<k -> panel pnlA, else pnlA+1
        int pAc = pnlA < 0 ? 0 : (pnlA > 11 ? 11 : pnlA);
        int pBi = pnlA + 1;
        int pBc = pBi < 0 ? 0 : (pBi > 11 ? 11 : pBi);
        const ushort* rA = (const ushort*)&DtH[pAc & 3][d][lane * DRS];
        const ushort* rB = (const ushort*)&DtH[pBc & 3][d][lane * DRS];
        float hv[32];
#pragma unroll
        for (int t = 0; t < 32; ++t) {
          const ushort* ptr = (t < k) ? rA : rB;
          hv[t] = __half2float(__ushort_as_half(ptr[t]));
        }
        // ---- boundary ring: read panel q; write bases for later windows ---
        float vbnd = BIGS;
        if (d > 0) vbnd = ring[d][q % 3][lane & 31];
        float* pW1 = &ring[dn][(q + 1) % 3][0];
        float* pW2 = &ring[dn][(q + 2) % 3][0];
        const int cb = 32 * q;
        const bool ext = extWave && (q == qstar);
        const bool steady = (q >= 2) && (q <= 11);

#define STEPX(T, EXT, GUARD) do {                                           \
        float s1 = wshr1f(cur);                                             \
        float bup = rdlane(vbnd, (T));                                      \
        s1 = (lane == 0) ? bup : s1;                                        \
        float dv = hv[(T)];                                                 \
        float m  = fminf(s2, fminf(s1, cur));                               \
        float md = __builtin_amdgcn_fmed3f(s2, s1, cur);                    \
        float mx = fmaxf(s2, fmaxf(s1, cur));                               \
        float e = 1.0f + fexp2(m - md) + fexp2(m - mx);                     \
        float val = dv + m - flog2(e);                                      \
        s2 = s1;                                                            \
        if (EXT) { if ((T) == t32 && lane == it) extv = val; }              \
        if (GUARD) {                                                        \
          if ((unsigned)(cb + (T) - lane) < 384u) cur = val;                \
          if (wr63 && (unsigned)(cb + (T) - 63) < 384u) {                   \
            if ((T) < 31) pW1[(T) + 1] = val; else pW2[0] = val;            \
          }                                                                 \
        } else {                                                            \
          cur = val;                                                        \
          if (wr63) { if ((T) < 31) pW1[(T) + 1] = val; else pW2[0] = val; }\
        }                                                                   \
      } while (0)

#define LOOP32(E, G) _Pragma("unroll") for (int T = 0; T < 32; ++T) STEPX(T, E, G);

        if (steady) {
          if (ext) { LOOP32(1, 0) } else { LOOP32(0, 0) }
        } else {
          if (ext) { LOOP32(1, 1) } else { LOOP32(0, 1) }
        }
#undef LOOP32
#undef STEPX
        if (ext && lane == it) dist[p_id] = extv * scale;
      }
    }
  }
}

// ---------------------------------------------------------------------------
// Loss reduction over 16 windows (validated rounds 1-21).
// ---------------------------------------------------------------------------
__device__ __forceinline__ float median5(const float* v) {
#pragma unroll
  for (int i = 0; i < 5; ++i) {
    int c = 0;
#pragma unroll
    for (int j = 0; j < 5; ++j)
      c += (v[j] < v[i]) || ((v[j] == v[i]) && (j < i));
    if (c == 2) return v[i];
  }
  return v[0];
}

__global__ void loss_kernel(const float* __restrict__ dist, float* __restrict__ out) {
  __shared__ float acc[NWIN];
  const int w = threadIdx.x;
  if (w < NWIN) {
    float dg[5], dn[10];
#pragma unroll
    for (int g = 0; g < 5; ++g)  dg[g] = dist[w * PERW + g];
#pragma unroll
    for (int n = 0; n < 10; ++n) dn[n] = dist[w * PERW + 5 + n];

    float lk = 0.f; int nz = 0;
#pragma unroll
    for (int g = 0; g < 5; ++g)
#pragma unroll
      for (int n = 0; n < 10; ++n) {
        float t = dg[g] + 1.0f - dn[n];
        if (t > 0.f) { lk += t; ++nz; }
      }
    float lv = lk / (1.0f + (float)nz);

    float sp = 0.f;
#pragma unroll
    for (int g = 0; g < 5; ++g) sp += dg[g];
    float only_pos = sp * (0.01f / 5.0f);

    float mg = median5(dg);
    float ms = median5(dn);

    int err = 0;
#pragma unroll
    for (int g = 0; g < 5; ++g) {
      err += ((dg[g] < mg) && (dn[g] < mg));
      err += ((dg[g] > ms) && (dn[g] > ms));
      err += ((dg[g] < mg) && (dn[5 + g] < mg));
      err += ((dg[g] > ms) && (dn[5 + g] > ms));
    }
    float offset = (float)err * (1.0f / 50.0f);

    acc[w] = lv + only_pos + offset;
  }
  __syncthreads();
  if (w == 0) {
    float s = 0.f;
#pragma unroll
    for (int i = 0; i < NWIN; ++i) s += acc[i];
    out[0] = s / (float)NWIN;
  }
}

// ---------------------------------------------------------------------------
extern "C" void kernel_launch(void* const* d_in, const int* in_sizes, int n_in,
                              void* d_out, int out_size, void* d_ws, size_t ws_size,
                              hipStream_t stream) {
  const float* data = (const float*)d_in[0];
  const int* lens   = (const int*)d_in[1];
  float* dist = (float*)d_ws;

  sdtw_kernel<<<NPAIR, 768, 0, stream>>>(data, lens, dist);
  loss_kernel<<<1, 64, 0, stream>>>(dist, (float*)d_out);
}

// Round 23
// 98.477 us; speedup vs baseline: 1.8642x; 1.0408x over previous
//
#include <hip/hip_runtime.h>
#include <hip/hip_fp16.h>

#define LQ 384
#define DF 64
#define NWIN 16
#define PERW 15      // NG + NF
#define STEPW 16     // 1 + NG + NF
#define NPAIR 240    // NWIN * PERW
#define NWAVE 6      // row-slabs (producer waves and consumer waves each)
#define PW 32        // D panel width (cols per production)
#define NPANEL 12    // 384 / PW
#define NRND 30      // continuous-flow rounds: 14 local + 3*5 skew + 1
#define BSTH 72      // fp16 B LDS row stride (halfs); 144 B = 16B-aligned rows
#define DRS 33       // fp16 D row stride (halfs)
#define C2  0.28853900817779268f   // 1/(5*ln2)  (pre-scale: R' = R*C2)
#define L2C 3.4657359027997265f    // 5*ln2      (unscale at extraction)
#define BIGS (1e9f * C2)           // BIG in scaled domain

typedef _Float16 h16x8 __attribute__((ext_vector_type(8)));
typedef float    f32x16 __attribute__((ext_vector_type(16)));

__device__ __forceinline__ float fexp2(float x) { return __builtin_amdgcn_exp2f(x); }
__device__ __forceinline__ float flog2(float x) { return __builtin_amdgcn_logf(x); }

// wave_shr:1 -- lane l gets lane l-1's value. lane0 keeps own (fixed up).
__device__ __forceinline__ float wshr1f(float x) {
  int xi = __float_as_int(x);
  return __int_as_float(__builtin_amdgcn_update_dpp(xi, xi, 0x138, 0xF, 0xF, false));
}
// wave_shl:1 -- lane l gets lane l+1's value (mirror of wshr1f).
__device__ __forceinline__ float wshl1f(float x) {
  int xi = __float_as_int(x);
  return __int_as_float(__builtin_amdgcn_update_dpp(xi, xi, 0x130, 0xF, 0xF, false));
}

// ---------------------------------------------------------------------------
// Continuous-flow soft-DTW (r22-validated, 102.5us / absmax 0.0, conflicts
// cleared by per-row rotation). This round: (1) boundary injection via a
// ROLLING DPP shift register (lane 0 always holds element T) instead of
// v_readlane -- removes the VALU->SALU->VALU hazard from the serial chain;
// (2) s_setprio(1) around the consumer chain (producers have >=1 round slack).
// ---------------------------------------------------------------------------
__global__ __launch_bounds__(768, 3) void sdtw_kernel(const float* __restrict__ data,
                                                      const int* __restrict__ lens,
                                                      float* __restrict__ dist) {
  __shared__ __align__(16) __half BshH[LQ * BSTH];           // 55296 B
  __shared__ __align__(16) __half DtH[4][NWAVE][64 * DRS];   // 101376 B (D*C2 fp16)
  __shared__ __align__(16) float  sqA[LQ];                   // 1536 B
  __shared__ __align__(16) float  sqB[LQ];                   // 1536 B
  __shared__ __align__(16) float  ring[NWAVE][3][32];        // 2304 B (162048 total)

  const int p_id = blockIdx.x;
  const int wwin = p_id / PERW;
  const int o = p_id - wwin * PERW;
  const int aRow = wwin * STEPW;
  const int bRow = aRow + 1 + o;
  const int la = lens[aRow];
  const int lb = lens[bRow];
  const int tid = threadIdx.x;
  const int w = tid >> 6;        // 0..11
  const int lane = tid & 63;

  const float* __restrict__ A  = data + (size_t)aRow * LQ * DF;
  const float* __restrict__ Bp = data + (size_t)bRow * LQ * DF;

  // ---- stage B (fp16) into LDS; sqA/sqB from fp32 global ----
  {
    const float4* B4 = (const float4*)Bp;
    for (int q = tid; q < LQ * 16; q += 768) {
      float4 v = B4[q];
      int row = q >> 4, c4 = (q & 15) << 2;
      uint u0 = __half_as_ushort(__float2half(v.x)) |
                ((uint)__half_as_ushort(__float2half(v.y)) << 16);
      uint u1 = __half_as_ushort(__float2half(v.z)) |
                ((uint)__half_as_ushort(__float2half(v.w)) << 16);
      uint2 qq; qq.x = u0; qq.y = u1;
      *(uint2*)&BshH[row * BSTH + c4] = qq;
    }
  }
  {
    const float* src = (tid < LQ) ? (A + (size_t)tid * DF) : (Bp + (size_t)(tid - LQ) * DF);
    const float4* S4 = (const float4*)src;
    float s = 0.f;
#pragma unroll
    for (int k = 0; k < 16; ++k) {
      float4 v = S4[k];
      s = fmaf(v.x, v.x, s); s = fmaf(v.y, v.y, s);
      s = fmaf(v.z, v.z, s); s = fmaf(v.w, v.w, s);
    }
    if (tid < LQ) sqA[tid] = s; else sqB[tid - LQ] = s;
  }
  __syncthreads();

  // extraction: R[la][lb] at wave wt, lane it, continuous step T* = (lb-1)+it
  const int wt = (la - 1) >> 6;
  const int it = (la - 1) & 63;
  const int Tstar = (lb - 1) + it;
  const int qstar = Tstar >> 5;
  const int t32 = Tstar & 31;
  const float scale = L2C / (float)(la + lb);

  if (w < NWAVE) {
    // =====================  GEMM (producer) waves: MFMA  ===================
    const int g = w;
    const int colL = lane & 31;
    const int kh = (lane >> 5) * 8;
    const int rq = 4 * (lane >> 5);
    const bool gActive = (64 * g < la);

    for (int rr = 0; rr < NRND; ++rr) {
      __syncthreads();
      const int p = rr - 3 * g;          // producer writes panel p this round
      if ((unsigned)p < (unsigned)NPANEL && gActive && (32 * p < lb)) {
        __half* DtW = &DtH[p & 3][g][0];
        float sb = sqB[PW * p + colL];
        h16x8 bfr[4];
#pragma unroll
        for (int ks = 0; ks < 4; ++ks)
          bfr[ks] = *(const h16x8*)&BshH[(size_t)(PW * p + colL) * BSTH + ks * 16 + kh];
#pragma unroll
        for (int mt = 0; mt < 2; ++mt) {
          const float* arow = A + (size_t)(64 * g + 32 * mt + colL) * DF + kh;
          f32x16 acc;
#pragma unroll
          for (int ii = 0; ii < 16; ++ii) acc[ii] = 0.f;
#pragma unroll
          for (int ks = 0; ks < 4; ++ks) {
            float4 a0 = *(const float4*)(arow + ks * 16);
            float4 a1 = *(const float4*)(arow + ks * 16 + 4);
            h16x8 af;
            af[0] = (_Float16)a0.x; af[1] = (_Float16)a0.y;
            af[2] = (_Float16)a0.z; af[3] = (_Float16)a0.w;
            af[4] = (_Float16)a1.x; af[5] = (_Float16)a1.y;
            af[6] = (_Float16)a1.z; af[7] = (_Float16)a1.w;
            acc = __builtin_amdgcn_mfma_f32_32x32x16_f16(af, bfr[ks], acc, 0, 0, 0);
          }
#pragma unroll
          for (int qq = 0; qq < 4; ++qq) {
            float4 sa = *(const float4*)&sqA[64 * g + 32 * mt + 8 * qq + rq];
            float sas[4] = {sa.x, sa.y, sa.z, sa.w};
#pragma unroll
            for (int ii = 0; ii < 4; ++ii) {
              int reg = qq * 4 + ii;
              int row = 32 * mt + 8 * qq + rq + ii;
              float dv = (sas[ii] + sb - 2.f * acc[reg]) * C2;
              DtW[row * DRS + ((colL + row) & 31)] = __float2half(dv);  // rotated
            }
          }
        }
      }
    }
  } else {
    // =====================  DP (consumer) waves: continuous flow  ==========
    const int d = w - NWAVE;            // slab: rows 64d+1..64d+64 (lane = row)
    const bool dActive = (64 * d < la);
    const int dn = (d + 1 < NWAVE) ? (d + 1) : 0;
    const bool wr63 = (lane == 63) && (d + 1 < NWAVE) && (64 * (d + 1) < la);
    const bool extWave = (d == wt);

    float cur = BIGS;                   // persists across rounds
    float s2  = (d == 0 && lane == 0) ? 0.f : BIGS;   // diag seed: R[0][0]=0
    float extv = 0.f;

    for (int rr = 0; rr < NRND; ++rr) {
      __syncthreads();
      const int q = rr - 3 * d - 1;     // local 32-step window index, 0..13
      if ((unsigned)q < 14u && dActive) {
        // ---- preload 32 D values: rotated layout -> position == t ---------
        const int c0 = 32 * q - lane;
        const int pnlA = c0 >> 5;
        const int k = 32 - (c0 & 31);   // t<k -> panel pnlA, else pnlA+1
        int pAc = pnlA < 0 ? 0 : (pnlA > 11 ? 11 : pnlA);
        int pBi = pnlA + 1;
        int pBc = pBi < 0 ? 0 : (pBi > 11 ? 11 : pBi);
        const ushort* rA = (const ushort*)&DtH[pAc & 3][d][lane * DRS];
        const ushort* rB = (const ushort*)&DtH[pBc & 3][d][lane * DRS];
        float hv[32];
#pragma unroll
        for (int t = 0; t < 32; ++t) {
          const ushort* ptr = (t < k) ? rA : rB;
          hv[t] = __half2float(__ushort_as_half(ptr[t]));
        }
        // ---- boundary ring: rolling register (lane 0 holds element T) -----
        float vbnd = BIGS;
        if (d > 0) vbnd = ring[d][q % 3][lane & 31];
        float vroll = vbnd;
        float* pW1 = &ring[dn][(q + 1) % 3][0];
        float* pW2 = &ring[dn][(q + 2) % 3][0];
        const int cb = 32 * q;
        const bool ext = extWave && (q == qstar);
        const bool steady = (q >= 2) && (q <= 11);

        __builtin_amdgcn_s_setprio(1);

#define STEPX(T, EXT, GUARD) do {                                           \
        float s1 = wshr1f(cur);                                             \
        s1 = (lane == 0) ? vroll : s1;                                      \
        vroll = wshl1f(vroll);                                              \
        float dv = hv[(T)];                                                 \
        float m  = fminf(s2, fminf(s1, cur));                               \
        float md = __builtin_amdgcn_fmed3f(s2, s1, cur);                    \
        float mx = fmaxf(s2, fmaxf(s1, cur));                               \
        float e = 1.0f + fexp2(m - md) + fexp2(m - mx);                     \
        float val = dv + m - flog2(e);                                      \
        s2 = s1;                                                            \
        if (EXT) { if ((T) == t32 && lane == it) extv = val; }              \
        if (GUARD) {                                                        \
          if ((unsigned)(cb + (T) - lane) < 384u) cur = val;                \
          if (wr63 && (unsigned)(cb + (T) - 63) < 384u) {                   \
            if ((T) < 31) pW1[(T) + 1] = val; else pW2[0] = val;            \
          }                                                                 \
        } else {                                                            \
          cur = val;                                                        \
          if (wr63) { if ((T) < 31) pW1[(T) + 1] = val; else pW2[0] = val; }\
        }                                                                   \
      } while (0)

#define LOOP32(E, G) _Pragma("unroll") for (int T = 0; T < 32; ++T) STEPX(T, E, G);

        if (steady) {
          if (ext) { LOOP32(1, 0) } else { LOOP32(0, 0) }
        } else {
          if (ext) { LOOP32(1, 1) } else { LOOP32(0, 1) }
        }
#undef LOOP32
#undef STEPX
        __builtin_amdgcn_s_setprio(0);
        if (ext && lane == it) dist[p_id] = extv * scale;
      }
    }
  }
}

// ---------------------------------------------------------------------------
// Loss reduction over 16 windows (validated rounds 1-22).
// ---------------------------------------------------------------------------
__device__ __forceinline__ float median5(const float* v) {
#pragma unroll
  for (int i = 0; i < 5; ++i) {
    int c = 0;
#pragma unroll
    for (int j = 0; j < 5; ++j)
      c += (v[j] < v[i]) || ((v[j] == v[i]) && (j < i));
    if (c == 2) return v[i];
  }
  return v[0];
}

__global__ void loss_kernel(const float* __restrict__ dist, float* __restrict__ out) {
  __shared__ float acc[NWIN];
  const int w = threadIdx.x;
  if (w < NWIN) {
    float dg[5], dn[10];
#pragma unroll
    for (int g = 0; g < 5; ++g)  dg[g] = dist[w * PERW + g];
#pragma unroll
    for (int n = 0; n < 10; ++n) dn[n] = dist[w * PERW + 5 + n];

    float lk = 0.f; int nz = 0;
#pragma unroll
    for (int g = 0; g < 5; ++g)
#pragma unroll
      for (int n = 0; n < 10; ++n) {
        float t = dg[g] + 1.0f - dn[n];
        if (t > 0.f) { lk += t; ++nz; }
      }
    float lv = lk / (1.0f + (float)nz);

    float sp = 0.f;
#pragma unroll
    for (int g = 0; g < 5; ++g) sp += dg[g];
    float only_pos = sp * (0.01f / 5.0f);

    float mg = median5(dg);
    float ms = median5(dn);

    int err = 0;
#pragma unroll
    for (int g = 0; g < 5; ++g) {
      err += ((dg[g] < mg) && (dn[g] < mg));
      err += ((dg[g] > ms) && (dn[g] > ms));
      err += ((dg[g] < mg) && (dn[5 + g] < mg));
      err += ((dg[g] > ms) && (dn[5 + g] > ms));
    }
    float offset = (float)err * (1.0f / 50.0f);

    acc[w] = lv + only_pos + offset;
  }
  __syncthreads();
  if (w == 0) {
    float s = 0.f;
#pragma unroll
    for (int i = 0; i < NWIN; ++i) s += acc[i];
    out[0] = s / (float)NWIN;
  }
}

// ---------------------------------------------------------------------------
extern "C" void kernel_launch(void* const* d_in, const int* in_sizes, int n_in,
                              void* d_out, int out_size, void* d_ws, size_t ws_size,
                              hipStream_t stream) {
  const float* data = (const float*)d_in[0];
  const int* lens   = (const int*)d_in[1];
  float* dist = (float*)d_ws;

  sdtw_kernel<<<NPAIR, 768, 0, stream>>>(data, lens, dist);
  loss_kernel<<<1, 64, 0, stream>>>(dist, (float*)d_out);
}